// Round 10
// baseline (28.649 us; speedup 1.0000x reference)
//
#include <hip/hip_runtime.h>
#include <math.h>

#define NATOMS 32
#define NMOL   64
#define RCRf 5.2f
#define RCAf 3.5f

// One WAVE per center (n,i); 4 waves (4 centers) per 256-thread block; 512
// blocks; ZERO __syncthreads. Each wave works in a private LDS slice; cross-
// lane handoff via in-wave s_waitcnt lgkmcnt(0).
//   setup: lanes 0..31 own atom j -> atomw/adatw; ballot-compact RCA nbrs.
//   pass loop (ceil(cnt/64), typ 1): lane p decodes pair in compacted space,
//     builds factorized record {f1[0..7], f2f[0..3]} (stride 13 floats);
//     per-wave ballot bucket-sort by species-pair px (bases -> SGPR-uniform,
//     stored to bcw[20]); E: lane accumulates its 5 features f=64q+lane
//     scanning only bucket 2q+hi (2 LDS reads + fma per record).
//   radial: lane owns radial feature `lane` (32-atom broadcast scan).
__global__ __launch_bounds__(256) void aev_kernel(const int* __restrict__ species,
                                                  const float* __restrict__ coords,
                                                  float* __restrict__ out) {
    const int wid  = threadIdx.x >> 6;
    const int lane = threadIdx.x & 63;
    const int center = (blockIdx.x << 2) + wid;    // n*32 + i
    const int n = center >> 5;
    const int i = center & 31;

    __shared__ float4 s_atom[4][NATOMS];   // dx, dy, dz, d
    __shared__ float4 s_adat[4][NATOMS];   // d, fcr, fca, species(float)
    __shared__ int    s_nbr [4][NATOMS];
    __shared__ float  s_rec [4][64*13];    // f1[0..7], f2f[0..3]; stride 13 (coprime 32)
    __shared__ int    s_bc  [4][20];       // base[0..9], cnt[10..19]

    float4* atomw = s_atom[wid];
    float4* adatw = s_adat[wid];
    int*    nbrw  = s_nbr[wid];
    float*  recw  = s_rec[wid];
    int*    bcw   = s_bc[wid];

    const unsigned long long ltm = (1ull << lane) - 1ull;  // lane<64: ok (lane63 -> 0x7fff..)

    // ---------- setup: lanes 0..31 own atom j = lane ----------
    float fca_v = 0.f;
    if (lane < NATOMS) {
        const float* cb = coords + (size_t)n*NATOMS*3;
        float dx = cb[lane*3+0] - cb[i*3+0];
        float dy = cb[lane*3+1] - cb[i*3+1];
        float dz = cb[lane*3+2] - cb[i*3+2];
        float d2 = dx*dx + dy*dy + dz*dz;
        float d  = sqrtf(d2 > 0.f ? d2 : 1.f);     // ref's where(d2>0,d2,1) guard
        bool self = (lane == i);
        float fr = (!self && d <= RCRf) ? (0.5f*__cosf(((float)M_PI/RCRf)*d) + 0.5f) : 0.f;
        fca_v    = (!self && d <= RCAf) ? (0.5f*__cosf(((float)M_PI/RCAf)*d) + 0.5f) : 0.f;
        atomw[lane] = make_float4(dx, dy, dz, d);
        adatw[lane] = make_float4(d, fr, fca_v, (float)species[n*NATOMS + lane]);
    }
    unsigned long long m = __ballot(fca_v > 0.f);      // full-wave context
    const int nn = (int)__popcll(m);
    if (fca_v > 0.f) nbrw[(int)__popcll(m & ltm)] = lane;
    asm volatile("s_waitcnt lgkmcnt(0)" ::: "memory"); // atom/nbr tables visible in-wave

    // ---------- radial: lane owns feature `lane` ----------
    const int rs = lane >> 4;
    const float shr = 0.9f + 0.26875f * (float)(lane & 15);   // SHF_R
    float racc = 0.f;
    #pragma unroll 8
    for (int j = 0; j < NATOMS; ++j) {
        float4 ad = adatw[j];                          // broadcast b128
        float dm = ad.x - shr;                         // ad.y==0 encodes mask
        racc += (ad.w == (float)rs) ? 0.25f * __expf(-16.f*dm*dm) * ad.y : 0.f;
    }

    // ---------- angular passes ----------
    const int cnt = (nn*(nn-1)) >> 1;
    const int passes = (cnt + 63) >> 6;
    const int M = 2*nn - 1;

    const float CZ[8] = { 0.98078528f,  0.83146961f,  0.55557023f,  0.19509032f,
                         -0.19509032f, -0.55557023f, -0.83146961f, -0.98078528f};
    const float SZ[8] = { 0.19509032f,  0.55557023f,  0.83146961f,  0.98078528f,
                          0.98078528f,  0.83146961f,  0.55557023f,  0.19509032f};
    const float SHA[4] = {0.9f, 1.55f, 2.2f, 2.85f};
    const int az = lane & 31;
    const int a = az >> 3, z = az & 7, hi = lane >> 5;
    const float czv = CZ[z], szv = SZ[z], sha = SHA[a];

    float acc[5] = {0.f, 0.f, 0.f, 0.f, 0.f};

    for (int pass = 0; pass < passes; ++pass) {
        asm volatile("s_waitcnt lgkmcnt(0)" ::: "memory");  // prev E reads done
        int p = (pass << 6) + lane;
        int px = -1;
        float4 v0, v1, v2;
        if (p < cnt) {
            float t = sqrtf((float)(M*M - 8*p));
            int jj = (int)(((float)M - t) * 0.5f);
            jj = max(0, min(jj, nn-2));
            while (jj*(2*nn-jj-1)/2 > p) --jj;              // <=2 fixup steps
            while ((jj+1)*(2*nn-jj-2)/2 <= p) ++jj;
            int kk = p - jj*(2*nn-jj-1)/2 + jj + 1;
            int j = nbrw[jj], k = nbrw[kk];
            float4 aj = atomw[j], ak = atomw[k];
            float4 dj = adatw[j], dk = adatw[k];
            float fc2 = 2.f * dj.z * dk.z;
            float dot = aj.x*ak.x + aj.y*ak.y + aj.z*ak.z;
            float c = 0.95f * dot * __builtin_amdgcn_rcpf(aj.w * ak.w);
            c = fminf(0.95f, fmaxf(-0.95f, c));
            float s = sqrtf(1.f - c*c);                     // sin(acos(c))
            float dmean = 0.5f * (aj.w + ak.w);
            int sj = (int)dj.w, sk = (int)dk.w;
            int lo = min(sj, sk), hs = max(sj, sk);
            px = ((lo*(9-lo)) >> 1) + (hs - lo);            // triu pair index, S=4
            v0.x = 0.5f + 0.5f*(c*CZ[0] + s*SZ[0]);
            v0.y = 0.5f + 0.5f*(c*CZ[1] + s*SZ[1]);
            v0.z = 0.5f + 0.5f*(c*CZ[2] + s*SZ[2]);
            v0.w = 0.5f + 0.5f*(c*CZ[3] + s*SZ[3]);
            v1.x = 0.5f + 0.5f*(c*CZ[4] + s*SZ[4]);
            v1.y = 0.5f + 0.5f*(c*CZ[5] + s*SZ[5]);
            v1.z = 0.5f + 0.5f*(c*CZ[6] + s*SZ[6]);
            v1.w = 0.5f + 0.5f*(c*CZ[7] + s*SZ[7]);
            #define POW32(q) { q = q*q; q = q*q; q = q*q; q = q*q; q = q*q; }
            POW32(v0.x) POW32(v0.y) POW32(v0.z) POW32(v0.w)
            POW32(v1.x) POW32(v1.y) POW32(v1.z) POW32(v1.w)
            #undef POW32
            float dm0 = dmean - SHA[0], dm1 = dmean - SHA[1];
            float dm2 = dmean - SHA[2], dm3 = dmean - SHA[3];
            v2.x = __expf(-8.f*dm0*dm0) * fc2;
            v2.y = __expf(-8.f*dm1*dm1) * fc2;
            v2.z = __expf(-8.f*dm2*dm2) * fc2;
            v2.w = __expf(-8.f*dm3*dm3) * fc2;
        }

        // ---- per-wave ballot bucket-sort (no atomics) ----
        int run = 0, slot = 0;
        #pragma unroll
        for (int b = 0; b < 10; ++b) {
            unsigned long long mb = __ballot(px == b);      // full-wave context
            if (px == b)   slot = run + (int)__popcll(mb & ltm);
            if (lane == b) { bcw[b] = run; bcw[10+b] = (int)__popcll(mb); }
            run += (int)__popcll(mb);
        }
        if (px >= 0) {
            float* r = recw + slot*13;
            *(float4*)(r+0) = v0;
            *(float4*)(r+4) = v1;
            *(float4*)(r+8) = v2;
        }
        asm volatile("s_waitcnt lgkmcnt(0)" ::: "memory");  // records + bc visible

        // ---- E: 5 features per lane, bucket-scan only ----
        #pragma unroll
        for (int q = 0; q < 5; ++q) {
            int b = 2*q + hi;
            int st = bcw[b], ct = bcw[10+b];
            float aq = 0.f;
            for (int r = st; r < st + ct; ++r)
                aq += recw[r*13 + z] * recw[r*13 + 8 + a];
            acc[q] += aq;
        }
    }

    // ---------- writes ----------
    float* oa = out + NMOL*NATOMS + (size_t)center * 384;
    oa[lane]       = racc;
    oa[64  + lane] = acc[0];
    oa[128 + lane] = acc[1];
    oa[192 + lane] = acc[2];
    oa[256 + lane] = acc[3];
    oa[320 + lane] = acc[4];
    if (lane == 0) out[center] = adatw[i].w;      // output 0: species (as f32)
}

extern "C" void kernel_launch(void* const* d_in, const int* in_sizes, int n_in,
                              void* d_out, int out_size, void* d_ws, size_t ws_size,
                              hipStream_t stream) {
    const int*   species = (const int*)d_in[0];
    const float* coords  = (const float*)d_in[1];
    float*       out     = (float*)d_out;
    aev_kernel<<<(NMOL*NATOMS)/4, 256, 0, stream>>>(species, coords, out);
}